// Round 8
// baseline (360.112 us; speedup 1.0000x reference)
//
#include <hip/hip_runtime.h>
#include <hip/hip_bf16.h>

#define Bb 128
#define LQ 32
#define LD 512
#define Hh 768
#define Cc 128

#define DBLOCKS ((Bb * LD) / 64)   // 1024 doc blocks (64 rows each)

typedef short bf16x8 __attribute__((ext_vector_type(8)));
typedef short bf16x4 __attribute__((ext_vector_type(4)));
typedef float f32x4 __attribute__((ext_vector_type(4)));

__device__ __forceinline__ short f2bf(float f) {
  union { float f; unsigned u; } v;
  v.f = f;
  unsigned u = v.u + (0x7FFFu + ((v.u >> 16) & 1u));  // RNE
  return (short)(u >> 16);
}

__device__ __forceinline__ float b2f(short s) {
  union { unsigned u; float f; } v;
  v.u = ((unsigned)(unsigned short)s) << 16;
  return v.f;
}

// K0: W (H,C) fp32 -> Wt (C,H) bf16 (transposed so B-chunks are row-contiguous)
__global__ __launch_bounds__(256) void k_wt(const float* __restrict__ W,
                                            short* __restrict__ Wt) {
  int idx = blockIdx.x * 256 + threadIdx.x;  // grid covers H*C exactly
  int h = idx >> 7;   // / 128
  int c = idx & 127;
  Wt[c * Hh + h] = f2bf(W[idx]);
}

// Fully fused: doc projection + query projection + importance + scores +
// partial max. One block per (batch, 64-doc-token chunk).
//
// R6/R7 post-mortem: source-level pipelining (2-deep prefetch, raw
// s_barrier) was NEUTRAL twice -- cross-block overlap already hides the
// per-block stalls (the m131-m140 lesson). The binding constraint per the
// counters was OCCUPANCY (25%, all pipes <20% busy). This version keeps the
// R4 K-loop verbatim and attacks TLP: dvt/lqt tiles stored as bf16 and
// packed into the dead GEMM-staging union, pm wave-reduced. LDS 53.0 ->
// 30.5 KB => 5 blocks/CU (LDS-wise), so the ENTIRE 1024-block grid is
// co-resident and every stall is covered by a neighbor block.
// Numerics: score-dot inputs gain one extra RNE bf16 rounding (rel ~2^-9
// on a 128-dot; small vs the existing 768-dot bf16 GEMM error).
//
// LDS layout (30464 B total):
//   [0,     29696) : GEMM staging (A 9216 + B 20480)
//                    -- after GEMM: dvt bf16[64][136] at 0 (17408 B),
//                                   lqt bf16[32][136] at 17408 (8704 B)
//   [29696, 29952) : dmsk[64]
//   [29952, 30464) : pm[4][32] f32 (per-wave maxima)
__global__ __launch_bounds__(256, 4) void k_fused(
    const float* __restrict__ dh, const float* __restrict__ qh,
    const short* __restrict__ Wt, const float* __restrict__ bcomp,
    const int* __restrict__ qmask, const int* __restrict__ dmask,
    const float* __restrict__ wstop, const float* __restrict__ bstop,
    float* __restrict__ partial) {
  constexpr int ASTR = 144;
  constexpr int BSTR = 160;
  constexpr int ASZ = 64 * ASTR;     // 9216
  constexpr int SSTR = 136;          // bf16 row stride (272 B; 2-way max)
  constexpr int NK = Hh / 64;        // 12 K-chunks
  __shared__ __align__(16) char smem[29696 + 256 + 512];

  char* bufA = smem;
  char* bufB = smem + ASZ;
  short* dvt = (short*)smem;                   // [64][136] bf16, after GEMM
  short* lqt = (short*)(smem + 17408);         // [32][136] bf16, after GEMM
  int* dmsk = (int*)(smem + 29696);            // [64]
  float* pm = (float*)(smem + 29696 + 256);    // [4][32]

  const int tid = threadIdx.x;
  const int w = tid >> 6;
  const int lane = tid & 63;
  const int quad = lane >> 4;
  const int lm = lane & 15;
  const bool isq = (w < 2);  // waves 0-1 also compute q rows w*16..w*16+15

  const int b = blockIdx.x >> 3;     // batch
  const int chunk = blockIdx.x & 7;  // 64-token chunk within doc
  const long row0b = (long)b * LD + chunk * 64;

  if (tid < 64) dmsk[tid] = dmask[row0b + tid];

  const float* gA = dh + (row0b + w * 16 + (lane >> 4)) * (long)Hh + (lane & 15) * 4;
  const short* gB = Wt + (w * 32 + (lane >> 3)) * Hh + (lane & 7) * 8;
  const float* gQ = qh + ((long)b * LQ + w * 16 + lm) * Hh + quad * 8;
  const int aoff = (w * 16 + (lane >> 4)) * ASTR + (lane & 15) * 8;
  const int boff = (w * 32 + (lane >> 3)) * BSTR + (lane & 7) * 16;

  f32x4 acc[8], accq[8];
#pragma unroll
  for (int j = 0; j < 8; ++j) acc[j] = (f32x4){0.f, 0.f, 0.f, 0.f};
#pragma unroll
  for (int j = 0; j < 8; ++j) accq[j] = (f32x4){0.f, 0.f, 0.f, 0.f};

  float4 ar[4], aq[4];
  bf16x8 br[4];
  // preload chunk 0
#pragma unroll
  for (int i = 0; i < 4; ++i) ar[i] = *(const float4*)(gA + i * 4 * Hh);
#pragma unroll
  for (int i = 0; i < 4; ++i) br[i] = *(const bf16x8*)(gB + i * 8 * Hh);
  if (isq) {
#pragma unroll
    for (int i = 0; i < 4; ++i)
      aq[i] = *(const float4*)(gQ + (i >> 1) * 32 + (i & 1) * 4);
  }

  for (int kk = 0; kk < NK; ++kk) {
    __syncthreads();  // previous chunk's readers done
    // pack + write chunk kk regs -> LDS
#pragma unroll
    for (int i = 0; i < 4; ++i) {
      bf16x4 p;
      p[0] = f2bf(ar[i].x); p[1] = f2bf(ar[i].y);
      p[2] = f2bf(ar[i].z); p[3] = f2bf(ar[i].w);
      *(bf16x4*)(bufA + aoff + i * 4 * ASTR) = p;
    }
#pragma unroll
    for (int i = 0; i < 4; ++i)
      *(bf16x8*)(bufB + boff + i * 8 * BSTR) = br[i];
    __syncthreads();  // LDS tile visible

    // Build this chunk's q fragments from aq NOW (before prefetch clobbers).
    bf16x8 fq0, fq1;
    if (isq) {
      fq0[0] = f2bf(aq[0].x); fq0[1] = f2bf(aq[0].y);
      fq0[2] = f2bf(aq[0].z); fq0[3] = f2bf(aq[0].w);
      fq0[4] = f2bf(aq[1].x); fq0[5] = f2bf(aq[1].y);
      fq0[6] = f2bf(aq[1].z); fq0[7] = f2bf(aq[1].w);
      fq1[0] = f2bf(aq[2].x); fq1[1] = f2bf(aq[2].y);
      fq1[2] = f2bf(aq[2].z); fq1[3] = f2bf(aq[2].w);
      fq1[4] = f2bf(aq[3].x); fq1[5] = f2bf(aq[3].y);
      fq1[6] = f2bf(aq[3].z); fq1[7] = f2bf(aq[3].w);
    }

    // issue next-chunk global loads; they have the whole compute phase to land
    {
      const long go = (kk + 1 < NK) ? (long)(kk + 1) * 64 : 0;
#pragma unroll
      for (int i = 0; i < 4; ++i) ar[i] = *(const float4*)(gA + i * 4 * Hh + go);
#pragma unroll
      for (int i = 0; i < 4; ++i) br[i] = *(const bf16x8*)(gB + i * 8 * Hh + go);
      if (isq) {
#pragma unroll
        for (int i = 0; i < 4; ++i)
          aq[i] = *(const float4*)(gQ + go + (i >> 1) * 32 + (i & 1) * 4);
      }
    }

    // compute chunk kk: doc 16x128 per wave; waves 0-1 add q 16x128 reusing fb
#pragma unroll
    for (int ks = 0; ks < 2; ++ks) {
      bf16x8 fa = *(const bf16x8*)(bufA + (w * 16 + lm) * ASTR + ks * 64 + quad * 16);
      const bf16x8 fqk = (ks == 0) ? fq0 : fq1;
#pragma unroll
      for (int j = 0; j < 8; ++j) {
        bf16x8 fb = *(const bf16x8*)(bufB + (j * 16 + lm) * BSTR + ks * 64 + quad * 16);
        acc[j] = __builtin_amdgcn_mfma_f32_16x16x32_bf16(fa, fb, acc[j], 0, 0, 0);
        if (isq)
          accq[j] = __builtin_amdgcn_mfma_f32_16x16x32_bf16(fqk, fb, accq[j], 0, 0, 0);
      }
    }
  }

  __syncthreads();  // all staging reads done -> safe to overwrite with dv/lq

  // Epilogue: bias, importance (quad butterfly, fp32), mask -> dvt bf16;
  // waves 0-1 also write masked q_vecs -> lqt bf16.
  float bc[8], wsv[8];
#pragma unroll
  for (int j = 0; j < 8; ++j) bc[j] = bcomp[j * 16 + lm];
#pragma unroll
  for (int j = 0; j < 8; ++j) wsv[j] = wstop[j * 16 + lm];
  const float bs = bstop[0];

#pragma unroll
  for (int r = 0; r < 4; ++r) {
    const int lrow = w * 16 + quad * 4 + r;  // chunk-local doc row
    float v[8];
#pragma unroll
    for (int j = 0; j < 8; ++j) v[j] = acc[j][r] + bc[j];
    float p = 0.f;
#pragma unroll
    for (int j = 0; j < 8; ++j) p += v[j] * wsv[j];
    p += __shfl_xor(p, 1);
    p += __shfl_xor(p, 2);
    p += __shfl_xor(p, 4);
    p += __shfl_xor(p, 8);
    const float imp = fmaxf(p + bs, 0.f);
    const float scale = imp * (float)dmsk[lrow];
#pragma unroll
    for (int j = 0; j < 8; ++j)
      dvt[lrow * SSTR + j * 16 + lm] = f2bf(v[j] * scale);
  }
  if (isq) {
    const int qrow0 = w * 16 + quad * 4;
#pragma unroll
    for (int r = 0; r < 4; ++r) {
      const int qrow = qrow0 + r;
      const float scale = (float)qmask[b * LQ + qrow];
#pragma unroll
      for (int j = 0; j < 8; ++j)
        lqt[qrow * SSTR + j * 16 + lm] = f2bf((accq[j][r] + bc[j]) * scale);
    }
  }
  __syncthreads();  // dv + lq tiles visible

  // Score phase: thread (qt,kt) owns q rows {qt, qt+16} x doc rows kt*4..+3;
  // bf16x8 LDS reads (16B per 8 c), shift-convert, fp32 FMA accumulate.
  const int qt = tid & 15;
  const int kt = tid >> 4;
  const int kbase = kt * 4;
  float a[2][4];
#pragma unroll
  for (int qi = 0; qi < 2; ++qi)
#pragma unroll
    for (int ki = 0; ki < 4; ++ki) a[qi][ki] = 0.f;

  for (int c = 0; c < Cc; c += 8) {
    bf16x8 q0 = *(const bf16x8*)&lqt[qt * SSTR + c];
    bf16x8 q1 = *(const bf16x8*)&lqt[(qt + 16) * SSTR + c];
    bf16x8 d0 = *(const bf16x8*)&dvt[(kbase + 0) * SSTR + c];
    bf16x8 d1 = *(const bf16x8*)&dvt[(kbase + 1) * SSTR + c];
    bf16x8 d2 = *(const bf16x8*)&dvt[(kbase + 2) * SSTR + c];
    bf16x8 d3 = *(const bf16x8*)&dvt[(kbase + 3) * SSTR + c];
#pragma unroll
    for (int e = 0; e < 8; ++e) {
      const float f0 = b2f(q0[e]);
      const float f1 = b2f(q1[e]);
      const float g0 = b2f(d0[e]);
      const float g1 = b2f(d1[e]);
      const float g2 = b2f(d2[e]);
      const float g3 = b2f(d3[e]);
      a[0][0] += f0 * g0; a[0][1] += f0 * g1;
      a[0][2] += f0 * g2; a[0][3] += f0 * g3;
      a[1][0] += f1 * g0; a[1][1] += f1 * g1;
      a[1][2] += f1 * g2; a[1][3] += f1 * g3;
    }
  }
  float m0 = -1000.f, m1 = -1000.f;
#pragma unroll
  for (int ki = 0; ki < 4; ++ki) {
    if (dmsk[kbase + ki]) {
      m0 = fmaxf(m0, a[0][ki]);
      m1 = fmaxf(m1, a[1][ki]);
    }
  }
  // Reduce over the wave's 4 kt groups (lanes differ in bits 4-5).
  m0 = fmaxf(m0, __shfl_xor(m0, 16));
  m0 = fmaxf(m0, __shfl_xor(m0, 32));
  m1 = fmaxf(m1, __shfl_xor(m1, 16));
  m1 = fmaxf(m1, __shfl_xor(m1, 32));
  if (lane < 16) {
    pm[w * 32 + lane] = m0;        // q row = lane
    pm[w * 32 + lane + 16] = m1;   // q row = lane + 16
  }
  __syncthreads();
  if (tid < LQ) {
    float mx = fmaxf(fmaxf(pm[tid], pm[32 + tid]),
                     fmaxf(pm[64 + tid], pm[96 + tid]));
    partial[((size_t)b * LQ + tid) * 8 + chunk] = mx;
  }
}

// Finalize: cls dot on raw CLS vectors, max over chunks, masked sum, merge.
__global__ __launch_bounds__(256) void k_final(
    const float* __restrict__ qh, const float* __restrict__ dh,
    const int* __restrict__ qmask, const float* __restrict__ partial,
    const float* __restrict__ merger, float* __restrict__ out) {
  const int b = blockIdx.x;
  const int tid = threadIdx.x;
  __shared__ float red[256];
  __shared__ float clss;
  const float* qc = qh + (size_t)b * LQ * Hh;  // q row 0 = CLS
  const float* dc = dh + (size_t)b * LD * Hh;  // d row 0 = CLS
  float s = 0.f;
  for (int h = tid; h < Hh; h += 256) s += qc[h] * dc[h];
  red[tid] = s;
  __syncthreads();
  for (int off = 128; off > 0; off >>= 1) {
    if (tid < off) red[tid] += red[tid + off];
    __syncthreads();
  }
  if (tid == 0) clss = red[0];
  __syncthreads();
  float t = 0.f;
  if (tid < LQ) {
    const float* pp = partial + ((size_t)b * LQ + tid) * 8;
    float mx = pp[0];
#pragma unroll
    for (int c = 1; c < 8; ++c) mx = fmaxf(mx, pp[c]);
    if (qmask[b * LQ + tid]) t = mx;
  }
  red[tid] = t;
  __syncthreads();
  for (int off = 128; off > 0; off >>= 1) {
    if (tid < off) red[tid] += red[tid + off];
    __syncthreads();
  }
  if (tid == 0) {
    float w = 1.f / (1.f + expf(-merger[0]));
    float cs = clss * w;
    float ts = red[0] * (1.f - w);
    out[b] = cs + ts;        // score
    out[Bb + b] = cs;        // cls_score
    out[2 * Bb + b] = ts;    // term_score
  }
}

extern "C" void kernel_launch(void* const* d_in, const int* in_sizes, int n_in,
                              void* d_out, int out_size, void* d_ws, size_t ws_size,
                              hipStream_t stream) {
  const float* qh  = (const float*)d_in[0];  // (B,LQ,H)
  const float* dh  = (const float*)d_in[1];  // (B,LD,H)
  const int*   qm  = (const int*)d_in[2];    // (B,LQ)
  const int*   dm  = (const int*)d_in[3];    // (B,LD)
  const float* W   = (const float*)d_in[4];  // (H,C)
  const float* bc  = (const float*)d_in[5];  // (C)
  const float* wst = (const float*)d_in[6];  // (C,1)
  const float* bst = (const float*)d_in[7];  // (1)
  const float* mrg = (const float*)d_in[8];  // (1)
  float* out = (float*)d_out;                // 3*B floats

  char* ws = (char*)d_ws;
  short* Wt  = (short*)ws;              // 192 KB bf16 W^T
  float* prt = (float*)(ws + 196608);   // 128 KB partial max

  k_wt<<<(Hh * Cc) / 256, 256, 0, stream>>>(W, Wt);
  k_fused<<<DBLOCKS, 256, 0, stream>>>(dh, qh, Wt, bc, qm, dm, wst, bst, prt);
  k_final<<<Bb, 256, 0, stream>>>(qh, dh, qm, prt, mrg, out);
}